// Round 3
// baseline (753.629 us; speedup 1.0000x reference)
//
#include <hip/hip_runtime.h>
#include <stdint.h>

// TokenChoiceTopKRouter: x[16384,4096] f32, W[64,4096] f32
//   logits = x @ W^T ; scores = sigmoid ; top-8 (lower index wins ties) ; histc
// d_out: [131072 scores | 131072 indices | 64 counts] — harness reads the
// WHOLE buffer as float32, so indices must be stored as FLOAT VALUES.
//
// fp32 GEMM + top-9 by logit; tokens with any adjacent-rank logit gap < GAP_T
// are flagged into d_ws and re-resolved exactly in fp64 by a second kernel.

#define M_TOK 16384
#define NEXP  64
#define KDIM  4096
#define BM    64
#define BK    64
#define GAP_T 2e-4f

__device__ __forceinline__ uint32_t order32(float f) {
    uint32_t b = __float_as_uint(f);
    return b ^ (((int32_t)b >> 31) | 0x80000000u);
}
__device__ __forceinline__ float unorder32(uint32_t u) {
    uint32_t b = (u & 0x80000000u) ? (u ^ 0x80000000u) : ~u;
    return __uint_as_float(b);
}
__device__ __forceinline__ uint64_t order64(double d) {
    uint64_t b = (uint64_t)__double_as_longlong(d);
    return b ^ (((int64_t)b >> 63) | 0x8000000000000000ull);
}
__device__ __forceinline__ double unorder64(uint64_t u) {
    uint64_t b = (u & 0x8000000000000000ull) ? (u ^ 0x8000000000000000ull) : ~u;
    return __longlong_as_double((int64_t)b);
}

__global__ __launch_bounds__(256, 1) void router_pass1(
    const float* __restrict__ x, const float* __restrict__ W,
    float* __restrict__ top_scores, float* __restrict__ top_idx,
    float* __restrict__ counts, unsigned int* __restrict__ flag_cnt,
    int* __restrict__ flag_list, int cap)
{
    __shared__ float xs[BK][BM + 4];     // xs[k][token]
    __shared__ float wsh[BK][NEXP + 4];  // wsh[k][expert]
    __shared__ float sc[BM][NEXP + 4];   // logits, token-major for epilogue
    __shared__ float hist[NEXP];

    const int tid = threadIdx.x;
    const int tx  = tid & 15;
    const int ty  = tid >> 4;
    const int m0  = blockIdx.x * BM;

    if (tid < NEXP) hist[tid] = 0.0f;

    float accm[4][4] = {};
    const int kq = tid & 15;
    const int lr = tid >> 4;

    for (int k0 = 0; k0 < KDIM; k0 += BK) {
        #pragma unroll
        for (int p = 0; p < 4; ++p) {
            const int row = lr + p * 16;
            const float4 v = *(const float4*)(x + (size_t)(m0 + row) * KDIM + k0 + kq * 4);
            xs[kq * 4 + 0][row] = v.x;
            xs[kq * 4 + 1][row] = v.y;
            xs[kq * 4 + 2][row] = v.z;
            xs[kq * 4 + 3][row] = v.w;
            const float4 w = *(const float4*)(W + (size_t)row * KDIM + k0 + kq * 4);
            wsh[kq * 4 + 0][row] = w.x;
            wsh[kq * 4 + 1][row] = w.y;
            wsh[kq * 4 + 2][row] = w.z;
            wsh[kq * 4 + 3][row] = w.w;
        }
        __syncthreads();
        // per-tile sub-accumulator caps fp32 error (~1e-6 total) so
        // GAP_T=2e-4 flagging has large margin
        float acct[4][4] = {};
        #pragma unroll
        for (int k = 0; k < BK; ++k) {
            const float4 a = *(const float4*)&xs[k][ty * 4];
            const float4 b = *(const float4*)&wsh[k][tx * 4];
            acct[0][0] += a.x * b.x; acct[0][1] += a.x * b.y; acct[0][2] += a.x * b.z; acct[0][3] += a.x * b.w;
            acct[1][0] += a.y * b.x; acct[1][1] += a.y * b.y; acct[1][2] += a.y * b.z; acct[1][3] += a.y * b.w;
            acct[2][0] += a.z * b.x; acct[2][1] += a.z * b.y; acct[2][2] += a.z * b.z; acct[2][3] += a.z * b.w;
            acct[3][0] += a.w * b.x; acct[3][1] += a.w * b.y; acct[3][2] += a.w * b.z; acct[3][3] += a.w * b.w;
        }
        #pragma unroll
        for (int i = 0; i < 4; ++i)
            #pragma unroll
            for (int j = 0; j < 4; ++j)
                accm[i][j] += acct[i][j];
        __syncthreads();
    }

    #pragma unroll
    for (int i = 0; i < 4; ++i)
        *(float4*)&sc[ty * 4 + i][tx * 4] =
            make_float4(accm[i][0], accm[i][1], accm[i][2], accm[i][3]);
    __syncthreads();

    // epilogue: wave w owns tokens w*16..w*16+15; lane == expert id
    const int wave = tid >> 6;
    const int lane = tid & 63;
    for (int t = wave * 16; t < wave * 16 + 16; ++t) {
        const float logit = sc[t][lane];
        uint32_t u = order32(logit);   // rank by logit (sigmoid monotonic)
        float win_logit = 0.0f;
        int   win_idx = 0;
        #pragma unroll
        for (int r = 0; r < 9; ++r) {  // 9 ranks -> all 8 adjacent boundaries
            unsigned long long key = ((unsigned long long)u << 32) | (uint32_t)(63 - lane);
            #pragma unroll
            for (int off = 32; off > 0; off >>= 1) {
                const unsigned long long o = __shfl_xor(key, off, 64);
                key = (key > o) ? key : o;
            }
            const int widx = 63 - (int)(key & 0xffffffffu);
            if (lane == r) {
                win_logit = unorder32((uint32_t)(key >> 32));
                win_idx = widx;
            }
            if (lane == widx) u = 0;   // remove winner
        }
        const float prev = __shfl_up(win_logit, 1, 64);
        const bool close = (lane >= 1 && lane <= 8) && (prev - win_logit < GAP_T);
        const unsigned long long bal = __ballot(close);
        const int token = m0 + t;
        if (lane == 0 && bal != 0ull) {
            const unsigned int slot = atomicAdd(flag_cnt, 1u);
            if ((int)slot < cap) flag_list[slot] = token;
        }
        if (lane < 8) {
            top_scores[(size_t)token * 8 + lane] = 1.0f / (1.0f + expf(-win_logit));
            top_idx[(size_t)token * 8 + lane]    = (float)win_idx;  // FLOAT value!
            atomicAdd(&hist[win_idx], 1.0f);
        }
    }
    __syncthreads();
    if (tid < NEXP) atomicAdd(&counts[tid], hist[tid]);
}

// fp64 exact re-resolution of flagged tokens
__global__ __launch_bounds__(256, 1) void router_fixup(
    const float* __restrict__ x, const float* __restrict__ W,
    float* __restrict__ top_scores, float* __restrict__ top_idx,
    float* __restrict__ counts, const unsigned int* __restrict__ flag_cnt,
    const int* __restrict__ flag_list, int cap)
{
    __shared__ double part[256];
    __shared__ double logits[NEXP];

    const int n = (int)min(*flag_cnt, (unsigned int)cap);
    const int t = threadIdx.x;
    const int e = t >> 2;      // expert 0..63
    const int q = t & 3;       // K quarter

    for (int i = blockIdx.x; i < n; i += gridDim.x) {
        const int tok = flag_list[i];
        float oldv = 0.0f;
        if (t < 8) oldv = top_idx[(size_t)tok * 8 + t];  // float-encoded index

        const float4* xr = (const float4*)(x + (size_t)tok * KDIM + q * 1024);
        const float4* wr = (const float4*)(W + (size_t)e * KDIM + q * 1024);
        double s = 0.0;
        for (int j = 0; j < 256; ++j) {
            const float4 a = xr[j];
            const float4 b = wr[j];
            s += (double)a.x * (double)b.x;
            s += (double)a.y * (double)b.y;
            s += (double)a.z * (double)b.z;
            s += (double)a.w * (double)b.w;
        }
        part[t] = s;
        __syncthreads();
        if (t < NEXP)
            logits[t] = part[4 * t] + part[4 * t + 1] + part[4 * t + 2] + part[4 * t + 3];
        __syncthreads();

        if (t < 64) {  // wave 0: exact top-8
            const int lane = t;
            // fp64 order bits; low 6 bits replaced by (63-lane) for the
            // lower-index-wins tie-break (2^-46 rel perturbation, harmless)
            uint64_t u = (order64(logits[lane]) & ~63ull) | (uint64_t)(63 - lane);
            #pragma unroll
            for (int r = 0; r < 8; ++r) {
                uint64_t key = u;
                #pragma unroll
                for (int off = 32; off > 0; off >>= 1) {
                    const uint64_t o = __shfl_xor((unsigned long long)key, off, 64);
                    key = (key > o) ? key : o;
                }
                const int widx = 63 - (int)(key & 63ull);
                if (lane == r) {
                    const double z = unorder64(key);
                    const double sc_ = 1.0 / (1.0 + exp(-z));
                    atomicAdd(&counts[(int)oldv], -1.0f);
                    atomicAdd(&counts[widx], 1.0f);
                    top_scores[(size_t)tok * 8 + lane] = (float)sc_;
                    top_idx[(size_t)tok * 8 + lane]    = (float)widx;  // FLOAT value!
                }
                if (lane == widx) u = 0;
            }
        }
        __syncthreads();
    }
}

extern "C" void kernel_launch(void* const* d_in, const int* in_sizes, int n_in,
                              void* d_out, int out_size, void* d_ws, size_t ws_size,
                              hipStream_t stream) {
    (void)in_sizes; (void)n_in; (void)out_size;
    const float* x = (const float*)d_in[0];
    const float* W = (const float*)d_in[1];

    float* top_scores = (float*)d_out;
    float* top_idx    = (float*)d_out + (size_t)M_TOK * 8;
    float* counts     = (float*)d_out + (size_t)2 * M_TOK * 8;

    unsigned int* flag_cnt  = (unsigned int*)d_ws;
    int*          flag_list = (int*)d_ws + 16;   // 64-byte offset
    int cap = (int)((ws_size > 64) ? ((ws_size - 64) / 4) : 0);
    if (cap > 16384) cap = 16384;

    hipMemsetAsync(counts, 0, NEXP * sizeof(float), stream);
    hipMemsetAsync(flag_cnt, 0, sizeof(unsigned int), stream);

    router_pass1<<<M_TOK / BM, 256, 0, stream>>>(x, W, top_scores, top_idx,
                                                 counts, flag_cnt, flag_list, cap);
    router_fixup<<<128, 256, 0, stream>>>(x, W, top_scores, top_idx,
                                          counts, flag_cnt, flag_list, cap);
}

// Round 4
// 545.130 us; speedup vs baseline: 1.3825x; 1.3825x over previous
//
#include <hip/hip_runtime.h>
#include <stdint.h>

// TokenChoiceTopKRouter: x[16384,4096] f32, W[64,4096] f32
//   logits = x@W^T ; sigmoid ; top-8 (lower index wins ties) ; histc
// d_out read back as ONE float32 stream: [scores | float-encoded indices | counts]
//
// Round 4: split-bf16 MFMA GEMM (xh*wh + xh*wl + xl*wh), HBM-bound on x.
//   kernel 0: W fp32 -> (Wh, Wl) bf16 in d_ws   (needs ws >= 128KB + 1MB)
//   kernel 1: fused GEMM + sigmoid + top-9 + gap-flag + hist (512 blocks, 2/CU)
//   kernel 2: fp64 coalesced fixup of flagged near-tie tokens

#define M_TOK 16384
#define NEXP  64
#define KDIM  4096
#define BM    32
#define BKW   64
#define NWIN  (KDIM / BKW)
#define ROWP  72            // padded LDS row (bf16 elems): 144 B, 16B-aligned, breaks 32-bank stride
#define SCW   68
#define GAP_T 2e-4f

typedef __attribute__((ext_vector_type(8))) short short8;
typedef __attribute__((ext_vector_type(4))) float floatx4;

__device__ __forceinline__ uint16_t f2bf(float f) {
    uint32_t u = __float_as_uint(f);
    return (uint16_t)((u + 0x7fffu + ((u >> 16) & 1u)) >> 16);   // RNE
}
__device__ __forceinline__ float bf2f(uint16_t h) {
    return __uint_as_float(((uint32_t)h) << 16);
}
__device__ __forceinline__ uint32_t order32(float f) {
    uint32_t b = __float_as_uint(f);
    return b ^ (((int32_t)b >> 31) | 0x80000000u);
}
__device__ __forceinline__ float unorder32(uint32_t u) {
    uint32_t b = (u & 0x80000000u) ? (u ^ 0x80000000u) : ~u;
    return __uint_as_float(b);
}
__device__ __forceinline__ uint64_t order64(double d) {
    uint64_t b = (uint64_t)__double_as_longlong(d);
    return b ^ (((int64_t)b >> 63) | 0x8000000000000000ull);
}
__device__ __forceinline__ double unorder64(uint64_t u) {
    uint64_t b = (u & 0x8000000000000000ull) ? (u ^ 0x8000000000000000ull) : ~u;
    return __longlong_as_double((int64_t)b);
}
__device__ __forceinline__ void cvt4(const float4 v, ushort4* h, ushort4* l) {
    uint16_t h0 = f2bf(v.x), h1 = f2bf(v.y), h2 = f2bf(v.z), h3 = f2bf(v.w);
    *h = make_ushort4(h0, h1, h2, h3);
    *l = make_ushort4(f2bf(v.x - bf2f(h0)), f2bf(v.y - bf2f(h1)),
                      f2bf(v.z - bf2f(h2)), f2bf(v.w - bf2f(h3)));
}

__global__ __launch_bounds__(256) void w_split(
    const float* __restrict__ W, uint16_t* __restrict__ Wh, uint16_t* __restrict__ Wl)
{
    const int idx = (blockIdx.x * 256 + threadIdx.x) * 4;   // 256 blocks cover 64*4096
    const float4 w = *(const float4*)(W + idx);
    ushort4 h, l;
    cvt4(w, &h, &l);
    *(ushort4*)(Wh + idx) = h;
    *(ushort4*)(Wl + idx) = l;
}

__global__ __launch_bounds__(256, 2) void router_pass1(
    const float* __restrict__ x,
    const uint16_t* __restrict__ Whg, const uint16_t* __restrict__ Wlg,
    float* __restrict__ top_scores, float* __restrict__ top_idx,
    float* __restrict__ counts, unsigned int* __restrict__ flag_cnt,
    int* __restrict__ flag_list, int cap)
{
    // 27648 bf16 elems = 55296 B: xh[2][32][72] xl[2][32][72] wh[2][64][72] wl[2][64][72]
    __shared__ __align__(16) uint16_t lds[27648];
    __shared__ float hist[NEXP];
    uint16_t* xh = lds;
    uint16_t* xl = xh + 2 * BM * ROWP;
    uint16_t* wh = xl + 2 * BM * ROWP;
    uint16_t* wl = wh + 2 * NEXP * ROWP;
    float* sc = (float*)wh;   // aliased AFTER K-loop (+barrier): [32][68] f32 = 8704 B

    const int tid = threadIdx.x;
    const int m0 = blockIdx.x * BM;
    if (tid < NEXP) hist[tid] = 0.0f;

    // staging roles
    const int xtok = tid >> 4;      // 0..15 (+16 for 2nd)
    const int xkq  = tid & 15;      // float4 quad along k
    const int wexp = tid >> 3;      // 0..31 (+32 for 2nd)
    const int woct = tid & 7;       // 8-bf16 chunk along k

    // wave -> output sub-tile
    const int wave = tid >> 6, lane = tid & 63;
    const int wm = wave >> 1, wn = wave & 1;
    const int quad = lane >> 4, r = lane & 15;
    const int arow  = wm * 16 + r;
    const int b0row = wn * 32 + r;
    const int b1row = wn * 32 + 16 + r;

    floatx4 acc0 = {0.f, 0.f, 0.f, 0.f}, acc1 = {0.f, 0.f, 0.f, 0.f};

    float4 xr0, xr1;
    uint4 whr0, whr1, wlr0, wlr1;
    auto issue_loads = [&](int k0) {
        xr0 = *(const float4*)(x + (size_t)(m0 + xtok) * KDIM + k0 + xkq * 4);
        xr1 = *(const float4*)(x + (size_t)(m0 + xtok + 16) * KDIM + k0 + xkq * 4);
        whr0 = *(const uint4*)(Whg + (size_t)wexp * KDIM + k0 + woct * 8);
        whr1 = *(const uint4*)(Whg + (size_t)(wexp + 32) * KDIM + k0 + woct * 8);
        wlr0 = *(const uint4*)(Wlg + (size_t)wexp * KDIM + k0 + woct * 8);
        wlr1 = *(const uint4*)(Wlg + (size_t)(wexp + 32) * KDIM + k0 + woct * 8);
    };

    issue_loads(0);
    for (int w = 0; w < NWIN; ++w) {
        const int buf = w & 1;
        {   // stage regs -> LDS buf  (other buffer than the one being computed)
            uint16_t* xhb = xh + buf * (BM * ROWP);
            uint16_t* xlb = xl + buf * (BM * ROWP);
            uint16_t* whb = wh + buf * (NEXP * ROWP);
            uint16_t* wlb = wl + buf * (NEXP * ROWP);
            ushort4 h, l;
            cvt4(xr0, &h, &l);
            *(ushort4*)(xhb + xtok * ROWP + xkq * 4) = h;
            *(ushort4*)(xlb + xtok * ROWP + xkq * 4) = l;
            cvt4(xr1, &h, &l);
            *(ushort4*)(xhb + (xtok + 16) * ROWP + xkq * 4) = h;
            *(ushort4*)(xlb + (xtok + 16) * ROWP + xkq * 4) = l;
            *(uint4*)(whb + wexp * ROWP + woct * 8) = whr0;
            *(uint4*)(whb + (wexp + 32) * ROWP + woct * 8) = whr1;
            *(uint4*)(wlb + wexp * ROWP + woct * 8) = wlr0;
            *(uint4*)(wlb + (wexp + 32) * ROWP + woct * 8) = wlr1;
        }
        __syncthreads();   // single barrier per window (double buffer makes it sufficient)
        if (w + 1 < NWIN) issue_loads((w + 1) * BKW);

        const uint16_t* xhb = xh + buf * (BM * ROWP);
        const uint16_t* xlb = xl + buf * (BM * ROWP);
        const uint16_t* whb = wh + buf * (NEXP * ROWP);
        const uint16_t* wlb = wl + buf * (NEXP * ROWP);
        #pragma unroll
        for (int s = 0; s < 2; ++s) {
            const int ko = s * 32 + quad * 8;
            const short8 ah  = *(const short8*)(xhb + arow * ROWP + ko);
            const short8 al  = *(const short8*)(xlb + arow * ROWP + ko);
            const short8 b0h = *(const short8*)(whb + b0row * ROWP + ko);
            const short8 b0l = *(const short8*)(wlb + b0row * ROWP + ko);
            const short8 b1h = *(const short8*)(whb + b1row * ROWP + ko);
            const short8 b1l = *(const short8*)(wlb + b1row * ROWP + ko);
            acc0 = __builtin_amdgcn_mfma_f32_16x16x32_bf16(al, b0h, acc0, 0, 0, 0);
            acc0 = __builtin_amdgcn_mfma_f32_16x16x32_bf16(ah, b0l, acc0, 0, 0, 0);
            acc0 = __builtin_amdgcn_mfma_f32_16x16x32_bf16(ah, b0h, acc0, 0, 0, 0);
            acc1 = __builtin_amdgcn_mfma_f32_16x16x32_bf16(al, b1h, acc1, 0, 0, 0);
            acc1 = __builtin_amdgcn_mfma_f32_16x16x32_bf16(ah, b1l, acc1, 0, 0, 0);
            acc1 = __builtin_amdgcn_mfma_f32_16x16x32_bf16(ah, b1h, acc1, 0, 0, 0);
        }
    }
    __syncthreads();   // all compute done before sc aliases the wh region

    // C/D layout: col = lane&15, row = quad*4 + reg   [verified mapping]
    #pragma unroll
    for (int i = 0; i < 4; ++i) {
        const int tok = wm * 16 + quad * 4 + i;
        sc[tok * SCW + wn * 32 + r]      = acc0[i];
        sc[tok * SCW + wn * 32 + 16 + r] = acc1[i];
    }
    __syncthreads();

    // top-9 by logit, flag near-ties, write outputs (validated in round 3)
    for (int t = wave * 8; t < wave * 8 + 8; ++t) {
        const float logit = sc[t * SCW + lane];
        uint32_t u = order32(logit);
        float win_logit = 0.0f;
        int win_idx = 0;
        #pragma unroll
        for (int rr = 0; rr < 9; ++rr) {
            unsigned long long key = ((unsigned long long)u << 32) | (uint32_t)(63 - lane);
            #pragma unroll
            for (int off = 32; off > 0; off >>= 1) {
                const unsigned long long o = __shfl_xor(key, off, 64);
                key = (key > o) ? key : o;
            }
            const int widx = 63 - (int)(key & 0xffffffffu);
            if (lane == rr) { win_logit = unorder32((uint32_t)(key >> 32)); win_idx = widx; }
            if (lane == widx) u = 0;
        }
        const float prev = __shfl_up(win_logit, 1, 64);
        const bool close = (lane >= 1 && lane <= 8) && (prev - win_logit < GAP_T);
        const unsigned long long bal = __ballot(close);
        const int token = m0 + t;
        if (lane == 0 && bal != 0ull) {
            const unsigned int slot = atomicAdd(flag_cnt, 1u);
            if ((int)slot < cap) flag_list[slot] = token;
        }
        if (lane < 8) {
            top_scores[(size_t)token * 8 + lane] = 1.0f / (1.0f + expf(-win_logit));
            top_idx[(size_t)token * 8 + lane] = (float)win_idx;   // float-encoded index
            atomicAdd(&hist[win_idx], 1.0f);
        }
    }
    __syncthreads();
    if (tid < NEXP) atomicAdd(&counts[tid], hist[tid]);
}

// fp64 exact re-resolution, coalesced: one block per flagged token,
// each wave streams whole W rows (wave -> 16 experts sequentially).
__global__ __launch_bounds__(256, 2) void router_fixup(
    const float* __restrict__ x, const float* __restrict__ W,
    float* __restrict__ top_scores, float* __restrict__ top_idx,
    float* __restrict__ counts, const unsigned int* __restrict__ flag_cnt,
    const int* __restrict__ flag_list, int cap)
{
    __shared__ double logits[NEXP];
    const int n = (int)min(*flag_cnt, (unsigned int)cap);
    const int tid = threadIdx.x;
    const int wave = tid >> 6, lane = tid & 63;

    for (int i = blockIdx.x; i < n; i += gridDim.x) {
        const int tok = flag_list[i];
        const float4* xp = (const float4*)(x + (size_t)tok * KDIM);
        for (int j = 0; j < 16; ++j) {
            const int e = wave * 16 + j;
            const float4* wp = (const float4*)(W + (size_t)e * KDIM);
            double s = 0.0;
            for (int c = lane; c < KDIM / 4; c += 64) {   // coalesced 1KB/instr
                const float4 a = xp[c], b = wp[c];
                s += (double)a.x * (double)b.x + (double)a.y * (double)b.y
                   + (double)a.z * (double)b.z + (double)a.w * (double)b.w;
            }
            #pragma unroll
            for (int off = 32; off > 0; off >>= 1) s += __shfl_down(s, off, 64);
            if (lane == 0) logits[e] = s;
        }
        __syncthreads();
        if (tid < 64) {
            const float oldv = (tid < 8) ? top_idx[(size_t)tok * 8 + tid] : 0.0f;
            // low 6 bits replaced by (63-tid): lower-index-wins tie-break (2^-46 rel, harmless)
            uint64_t u = (order64(logits[tid]) & ~63ull) | (uint64_t)(63 - tid);
            #pragma unroll
            for (int rr = 0; rr < 8; ++rr) {
                uint64_t key = u;
                #pragma unroll
                for (int off = 32; off > 0; off >>= 1) {
                    const uint64_t o = __shfl_xor((unsigned long long)key, off, 64);
                    key = (key > o) ? key : o;
                }
                const int widx = 63 - (int)(key & 63ull);
                if (tid == rr) {
                    const double z = unorder64(key);
                    atomicAdd(&counts[(int)oldv], -1.0f);
                    atomicAdd(&counts[widx], 1.0f);
                    top_scores[(size_t)tok * 8 + tid] = (float)(1.0 / (1.0 + exp(-z)));
                    top_idx[(size_t)tok * 8 + tid] = (float)widx;
                }
                if (tid == widx) u = 0;
            }
        }
        __syncthreads();
    }
}

extern "C" void kernel_launch(void* const* d_in, const int* in_sizes, int n_in,
                              void* d_out, int out_size, void* d_ws, size_t ws_size,
                              hipStream_t stream) {
    (void)in_sizes; (void)n_in; (void)out_size; (void)ws_size;
    const float* x = (const float*)d_in[0];
    const float* W = (const float*)d_in[1];

    float* top_scores = (float*)d_out;
    float* top_idx    = (float*)d_out + (size_t)M_TOK * 8;
    float* counts     = (float*)d_out + (size_t)2 * M_TOK * 8;

    // ws layout: [0,64B) flag_cnt | [64B,128KB) flag_list | [128KB,640KB) Wh | [640KB,1152KB) Wl
    unsigned int* flag_cnt  = (unsigned int*)d_ws;
    int*          flag_list = (int*)d_ws + 16;
    uint16_t*     Whg = (uint16_t*)((char*)d_ws + (128 << 10));
    uint16_t*     Wlg = Whg + (size_t)NEXP * KDIM;
    const int cap = 16384;

    hipMemsetAsync(counts, 0, NEXP * sizeof(float), stream);
    hipMemsetAsync(flag_cnt, 0, sizeof(unsigned int), stream);

    w_split<<<256, 256, 0, stream>>>(W, Whg, Wlg);
    router_pass1<<<M_TOK / BM, 256, 0, stream>>>(x, Whg, Wlg, top_scores, top_idx,
                                                 counts, flag_cnt, flag_list, cap);
    router_fixup<<<256, 256, 0, stream>>>(x, W, top_scores, top_idx,
                                          counts, flag_cnt, flag_list, cap);
}